// Round 5
// baseline (149.285 us; speedup 1.0000x reference)
//
#include <hip/hip_runtime.h>
#include <hip/hip_bf16.h>
#include <hip/hip_fp16.h>

#define LN_EPS 1e-5f
#define NREP 8

typedef _Float16 f16x2 __attribute__((ext_vector_type(2)));

// XCD-local (no sc1) packed-f16 atomic add: RMW executes in the requester
// XCD's TCC (L2). Atomic only within that XCD — callers must guarantee all
// writers of a given address are on the same XCD (we use replica[XCC_ID]).
__device__ __forceinline__ void pk_atomic_add_xcd(_Float16* p, float v0, float v1) {
  f16x2 v;
  v.x = (_Float16)v0;
  v.y = (_Float16)v1;
  asm volatile("global_atomic_pk_add_f16 %0, %1, off" :: "v"(p), "v"(v) : "memory");
}

__device__ __forceinline__ int xcc_id() {
  int x;
  asm volatile("s_getreg_b32 %0, hwreg(HW_REG_XCC_ID)" : "=s"(x));
  return x & (NREP - 1);
}

// ---------------------------------------------------------------------------
// Algebra: per-edge contribution to the (pre-mean) node feature is
//   contrib[col] = sum_h a_h (rel . M_h[col] + cv_h[col])
// linear in f = (a0,a1,a2, rx,ry,rz, a_h*rel_i for h<3, 1)  [16 dims]
// (sum_h a_h = 1 eliminates head 3). scatter-mean(contrib) = scatter-mean(f) @ T.
// f[15] = 1 doubles as the count. f accumulated in f16 packed atomics into
// 8 XCD-private replicas (XCD-local L2 atomics); node kernel sums replicas.
//
// ws layout:
//   [0, 8*N*16) _Float16   f-sum replicas (32 B per node per replica)
//   then floats: flag (1) pad(7), coef (4*10), T (16*32)
// ---------------------------------------------------------------------------

__global__ void precompute_kernel(const float* __restrict__ Wq,
                                  const float* __restrict__ bq,
                                  const float* __restrict__ Wk,
                                  const float* __restrict__ bk,
                                  const float* __restrict__ Wv,
                                  const float* __restrict__ bv,
                                  const float* __restrict__ Wout,
                                  const int* __restrict__ ei,
                                  float* __restrict__ flag,
                                  float* __restrict__ coef,
                                  float* __restrict__ T) {
  __shared__ float sM[4][3][32];
  __shared__ float sCv[4][32];
  int t = threadIdx.x;
  const float scale = 0.17677669529663687f;  // 1/sqrt(32)

  if (t == 0) {
    // int64 edge_index layout probe: odd 32-bit words of 8 random indices
    // in [0,1e5) are all zero iff the buffer is little-endian int64.
    int all_zero = 1;
    for (int i = 0; i < 8; ++i) all_zero &= (ei[2 * i + 1] == 0);
    flag[0] = all_zero ? 1.0f : 0.0f;
  }

  {
    int h = t >> 5, o = t & 31;
    float m0 = 0, m1 = 0, m2 = 0, cv = 0;
    for (int d = 0; d < 32; ++d) {
      int j = h * 32 + d;
      float w = Wout[j * 32 + o];
      m0 += Wv[0 * 128 + j] * w;
      m1 += Wv[1 * 128 + j] * w;
      m2 += Wv[2 * 128 + j] * w;
      cv += bv[j] * w;
    }
    sM[h][0][o] = m0;
    sM[h][1][o] = m1;
    sM[h][2][o] = m2;
    sCv[h][o] = cv;
  }

  if (t < 40) {
    int h = t / 10, j = t % 10;
    float acc = 0;
    for (int d = 0; d < 32; ++d) {
      int idx = h * 32 + d;
      float q0 = Wq[0 * 128 + idx], q1 = Wq[1 * 128 + idx], q2 = Wq[2 * 128 + idx];
      float k0 = Wk[0 * 128 + idx], k1 = Wk[1 * 128 + idx], k2 = Wk[2 * 128 + idx];
      float bqv = bq[idx], bkv = bk[idx];
      float v;
      switch (j) {
        case 0: v = q0 * k0; break;
        case 1: v = q1 * k1; break;
        case 2: v = q2 * k2; break;
        case 3: v = q0 * k1 + q1 * k0; break;
        case 4: v = q0 * k2 + q2 * k0; break;
        case 5: v = q1 * k2 + q2 * k1; break;
        case 6: v = q0 * bkv + k0 * bqv; break;
        case 7: v = q1 * bkv + k1 * bqv; break;
        case 8: v = q2 * bkv + k2 * bqv; break;
        default: v = bqv * bkv; break;
      }
      acc += v;
    }
    coef[h * 10 + j] = acc * scale;
  }

  __syncthreads();

  for (int idx = t; idx < 512; idx += 128) {
    int j = idx >> 5, col = idx & 31;
    float v;
    if (j < 3)        v = sCv[j][col] - sCv[3][col];
    else if (j < 6)   v = sM[3][j - 3][col];
    else if (j < 15)  { int h = (j - 6) / 3, i = (j - 6) % 3; v = sM[h][i][col] - sM[3][i][col]; }
    else              v = sCv[3][col];
    T[idx] = v;
  }
}

__device__ __forceinline__ void sel_comp(int comp, int& pa, int& pr) {
  if (comp < 3)       { pa = comp;           pr = 3; }
  else if (comp < 6)  { pa = 3;              pr = comp - 3; }
  else if (comp < 15) { pa = (comp - 6) / 3; pr = (comp - 6) % 3; }
  else                { pa = 3;              pr = 3; }
}

__global__ void edge_kernel(const float* __restrict__ pos,
                            const int* __restrict__ ei, int E, int N,
                            const float* __restrict__ flag,
                            const float* __restrict__ coef,
                            _Float16* __restrict__ fsums) {
  const int lane = threadIdx.x & 31;
  const int group = (blockIdx.x * blockDim.x + threadIdx.x) >> 5;
  const int base = group * 32;
  if (base >= E) return;

  _Float16* frep = fsums + (size_t)xcc_id() * N * 16;

  const int i64 = (flag[0] != 0.0f) ? 1 : 0;
  const int valid_n = min(32, E - base);
  const int e = base + lane;

  int c = 0;
  float rx = 0, ry = 0, rz = 0, a0 = 0, a1 = 0, a2 = 0;
  if (lane < valid_n) {
    int r, cc;
    if (i64) {
      r = ei[2 * (size_t)e];
      cc = ei[2 * ((size_t)E + e)];
    } else {
      r = ei[e];
      cc = ei[E + e];
    }
    c = cc;
    rx = pos[r * 3 + 0] - pos[cc * 3 + 0];
    ry = pos[r * 3 + 1] - pos[cc * 3 + 1];
    rz = pos[r * 3 + 2] - pos[cc * 3 + 2];
    float s[4];
#pragma unroll
    for (int h = 0; h < 4; ++h) {
      const float* cf = coef + h * 10;
      s[h] = cf[9] + rx * cf[6] + ry * cf[7] + rz * cf[8] + rx * rx * cf[0] +
             ry * ry * cf[1] + rz * rz * cf[2] + rx * ry * cf[3] +
             rx * rz * cf[4] + ry * rz * cf[5];
    }
    float mx = fmaxf(fmaxf(s[0], s[1]), fmaxf(s[2], s[3]));
    float e0 = __expf(s[0] - mx), e1 = __expf(s[1] - mx);
    float e2 = __expf(s[2] - mx), e3 = __expf(s[3] - mx);
    float inv = 1.0f / (e0 + e1 + e2 + e3);
    a0 = e0 * inv; a1 = e1 * inv; a2 = e2 * inv;   // a3 never needed
  }

  // 8 half2 slots per edge; 32 lanes handle 4 edges per iteration.
  const int pair = lane & 7;   // half2 slot: comps (2*pair, 2*pair+1)
  const int sub  = lane >> 3;  // which of the 4 in-flight edges
  int pa0, pr0, pa1, pr1;
  sel_comp(2 * pair, pa0, pr0);
  sel_comp(2 * pair + 1, pa1, pr1);

  for (int t2 = 0; t2 < valid_n; t2 += 4) {
    const int src = t2 + sub;
    float tx = __shfl(rx, src, 32);
    float ty = __shfl(ry, src, 32);
    float tz = __shfl(rz, src, 32);
    float b0 = __shfl(a0, src, 32);
    float b1 = __shfl(a1, src, 32);
    float b2 = __shfl(a2, src, 32);
    int   ct = __shfl(c,  src, 32);
    float A0 = (pa0 == 0) ? b0 : (pa0 == 1) ? b1 : (pa0 == 2) ? b2 : 1.0f;
    float R0 = (pr0 == 0) ? tx : (pr0 == 1) ? ty : (pr0 == 2) ? tz : 1.0f;
    float A1 = (pa1 == 0) ? b0 : (pa1 == 1) ? b1 : (pa1 == 2) ? b2 : 1.0f;
    float R1 = (pr1 == 0) ? tx : (pr1 == 1) ? ty : (pr1 == 2) ? tz : 1.0f;
    if (src < valid_n)
      pk_atomic_add_xcd(frep + (size_t)ct * 16 + 2 * pair, A0 * R0, A1 * R1);
  }
}

__global__ void node_kernel(const _Float16* __restrict__ fsums,
                            const float* __restrict__ T,
                            const float* __restrict__ bout,
                            const float* __restrict__ gamma,
                            const float* __restrict__ beta,
                            float* __restrict__ out, int N) {
  int tid = blockIdx.x * blockDim.x + threadIdx.x;
  int node = tid >> 5;
  int col = tid & 31;
  if (node >= N) return;

  const size_t rep_stride = (size_t)N * 16;
  const size_t idx = (size_t)node * 16 + (col & 15);
  float myf = 0.0f;
#pragma unroll
  for (int rep = 0; rep < NREP; ++rep)
    myf += (float)fsums[rep * rep_stride + idx];

  float cnt = __shfl(myf, 15, 32);
  float invc = 1.0f / fmaxf(cnt, 1.0f);

  float acc = bout[col];
#pragma unroll
  for (int j = 0; j < 16; ++j) {
    float fj = __shfl(myf, j, 32);
    acc = fmaf(fj * invc, T[j * 32 + col], acc);
  }

  float sx = acc, sx2 = acc * acc;
#pragma unroll
  for (int off = 16; off >= 1; off >>= 1) {
    sx += __shfl_xor(sx, off);
    sx2 += __shfl_xor(sx2, off);
  }
  float mu = sx * (1.0f / 32.0f);
  float var = sx2 * (1.0f / 32.0f) - mu * mu;
  float inv = rsqrtf(var + LN_EPS);
  float y = (acc - mu) * inv * gamma[col] + beta[col];
  float o = y * (1.0f / (1.0f + __expf(-y)));  // SiLU
  out[(size_t)node * 32 + col] = o;
}

extern "C" void kernel_launch(void* const* d_in, const int* in_sizes, int n_in,
                              void* d_out, int out_size, void* d_ws, size_t ws_size,
                              hipStream_t stream) {
  const float* pos  = (const float*)d_in[0];
  const int*   ei   = (const int*)d_in[1];
  const float* Wq   = (const float*)d_in[2];
  const float* bq   = (const float*)d_in[3];
  const float* Wk   = (const float*)d_in[4];
  const float* bk   = (const float*)d_in[5];
  const float* Wv   = (const float*)d_in[6];
  const float* bv   = (const float*)d_in[7];
  const float* Wout = (const float*)d_in[8];
  const float* bout = (const float*)d_in[9];
  const float* gam  = (const float*)d_in[10];
  const float* bet  = (const float*)d_in[11];

  const int N = in_sizes[0] / 3;
  const int E = in_sizes[1] / 2;

  _Float16* fsums = (_Float16*)d_ws;   // NREP * N*16 halves (N*32 B each)
  float* tail = (float*)((char*)d_ws + (size_t)NREP * N * 32);
  float* flag = tail;            // 1 (+7 pad)
  float* coef = flag + 8;        // 40
  float* T    = coef + 40;       // 512

  hipMemsetAsync(d_ws, 0, (size_t)NREP * N * 16 * sizeof(_Float16), stream);

  precompute_kernel<<<1, 128, 0, stream>>>(Wq, bq, Wk, bk, Wv, bv, Wout, ei,
                                           flag, coef, T);

  int edge_blocks = (E + 255) / 256;  // 8 groups of 32 edges per 256-block
  edge_kernel<<<edge_blocks, 256, 0, stream>>>(pos, ei, E, N, flag, coef, fsums);

  int node_blocks = (int)(((size_t)N * 32 + 255) / 256);
  node_kernel<<<node_blocks, 256, 0, stream>>>(fsums, T, bout, gam, bet,
                                               (float*)d_out, N);

  (void)n_in; (void)out_size; (void)ws_size;
}